// Round 13
// baseline (137.443 us; speedup 1.0000x reference)
//
#include <hip/hip_runtime.h>

#define D 128
#define SCALE 0.25f
#define NXCD 8
#define CAP 16     // per-(node,xcd) bucket; per-shard count ~Poisson(2)

typedef __attribute__((ext_vector_type(8))) short bf16x8;
typedef __attribute__((ext_vector_type(4))) float f32x4;
typedef __attribute__((ext_vector_type(4))) unsigned int u32x4;
typedef __attribute__((ext_vector_type(2))) unsigned int u32x2;
typedef unsigned short u16;

#if __has_builtin(__builtin_amdgcn_fdot2_f32_bf16)
#define HAS_DOT2 1
typedef __attribute__((ext_vector_type(2))) __bf16 bf16x2;
__device__ inline float fdot2bf(unsigned a, unsigned b, float c) {
  return __builtin_amdgcn_fdot2_f32_bf16(__builtin_bit_cast(bf16x2, a),
                                         __builtin_bit_cast(bf16x2, b), c, false);
}
#else
#define HAS_DOT2 0
#endif

__device__ inline short f2bf(float f) {          // RNE float->bf16
  unsigned u = __float_as_uint(f);
  u += 0x7fff + ((u >> 16) & 1);
  return (short)(u >> 16);
}
__device__ inline float bf2f(u16 h) { return __uint_as_float(((unsigned)h) << 16); }
__device__ inline unsigned packbf2(float lo, float hi) {   // round-half-up pack
  unsigned a = __float_as_uint(lo) + 0x8000u;
  unsigned b = __float_as_uint(hi) + 0x8000u;
  return (a >> 16) | (b & 0xffff0000u);
}
// quad-lane butterfly add via DPP (pure VALU): l^1 then l^2
__device__ inline float quad_reduce_add(float p) {
  float t1 = __uint_as_float((unsigned)__builtin_amdgcn_update_dpp(
      0, (int)__float_as_uint(p), 0xB1, 0xf, 0xf, true));
  p += t1;
  float t2 = __uint_as_float((unsigned)__builtin_amdgcn_update_dpp(
      0, (int)__float_as_uint(p), 0x4E, 0xf, 0xf, true));
  return p + t2;
}

// ---- shared build phase: 8 consecutive edges per thread.
// esrc/etgt are SEPARATE pointers (esrc=ei, etgt=ei+E_total); elim is the
// edge-count bound. (R12 bug: one param served as both bound and tgt offset.)
__device__ inline void build_edges8(const int* __restrict__ esrc,
                                    const int* __restrict__ etgt,
                                    int* __restrict__ cntx, u16* __restrict__ etgtx,
                                    int n, int elim, int e0base) {
  int xcd;
  asm volatile("s_getreg_b32 %0, hwreg(HW_REG_XCC_ID)" : "=s"(xcd));
  xcd &= (NXCD - 1);
  const int base = e0base + (int)threadIdx.x * 8;
  int s[8], t[8];
  if (base + 7 < elim) {
    *(int4*)&s[0] = *(const int4*)(esrc + base);
    *(int4*)&s[4] = *(const int4*)(esrc + base + 4);
    *(int4*)&t[0] = *(const int4*)(etgt + base);
    *(int4*)&t[4] = *(const int4*)(etgt + base + 4);
    int pos[8];
#pragma unroll
    for (int u = 0; u < 8; ++u)
      pos[u] = atomicAdd(&cntx[(size_t)xcd * n + s[u]], 1);
#pragma unroll
    for (int u = 0; u < 8; ++u)
      if (pos[u] < CAP) etgtx[(((size_t)xcd * n + s[u]) << 4) + pos[u]] = (u16)t[u];
  } else {
    for (int u = 0; u < 8; ++u) {
      const int i = base + u;
      if (i < elim) {
        const int ss = esrc[i];
        const int tt = etgt[i];
        const int pos = atomicAdd(&cntx[(size_t)xcd * n + ss], 1);
        if (pos < CAP) etgtx[(((size_t)xcd * n + ss) << 4) + pos] = (u16)tt;
      }
    }
  }
}

// ------ dispatch 1: weight swizzle (32 blocks) + build of edges [0, e1) ------
// wseq[((ct*4+kk)*64+lane)*8+j] = W[ct*16+(lane&15)][kk*32+(lane>>4)*8+j]
__global__ __launch_bounds__(256) void wcvt_build(
    const float* __restrict__ Wqkv, const float* __restrict__ Wout,
    short* __restrict__ wseq, const int* __restrict__ esrc,
    const int* __restrict__ etgt, int* __restrict__ cntx,
    u16* __restrict__ etgtx, int n, int e1) {
  if ((int)blockIdx.x >= 32) {     // ---- build part ----
    build_edges8(esrc, etgt, cntx, etgtx, n, e1, ((int)blockIdx.x - 32) * 2048);
    return;
  }
  const int idx = blockIdx.x * 256 + threadIdx.x;   // 8192 exact
  const int ct = idx >> 8, kk = (idx >> 6) & 3, lane = idx & 63;
  const float* W = (ct < 24) ? Wqkv : Wout;
  const int row = ((ct < 24) ? ct : ct - 24) * 16 + (lane & 15);
  const int col = kk * 32 + ((lane >> 4) << 3);
  const float* s = W + (size_t)row * 128 + col;
  bf16x8 o;
#pragma unroll
  for (int j = 0; j < 8; ++j) o[j] = f2bf(s[j]);
  *(bf16x8*)(wseq + (size_t)idx * 8) = o;
}

// ------ dispatch 2: build of edges [e1, E) (blocks FIRST) + QKV MFMA ------
// QKV: SWAPPED operands (A=W, B=X) -> lane holds out[row=l&15][4 consecutive
// cols] => contiguous 8B (q) / 16B (kv-interleaved) stores.
__global__ __launch_bounds__(256) void qkv_build(
    const float* __restrict__ embeds, const short* __restrict__ wseq,
    short* __restrict__ qb, short* __restrict__ kv,
    const int* __restrict__ esrc, const int* __restrict__ etgt,
    int* __restrict__ cntx, u16* __restrict__ etgtx,
    int n, int E, int e1, int nbuild) {
  if ((int)blockIdx.x < nbuild) {  // ---- build part (edges [e1, E)) ----
    build_edges8(esrc, etgt, cntx, etgtx, n, E, e1 + (int)blockIdx.x * 2048);
    return;
  }

  // ---- QKV ----
  const int lane = threadIdx.x & 63;
  const int wave = threadIdx.x >> 6;
  const int m0 = ((int)blockIdx.x - nbuild) * 32 + (wave >> 1) * 16;
  const int chalf = wave & 1;
  const int r16 = lane & 15;
  const int kbase = (lane >> 4) * 8;
  const int arow = min(m0 + r16, n - 1);

  f32x4 alo[4], ahi[4];
#pragma unroll
  for (int kk = 0; kk < 4; ++kk) {
    const float* s = embeds + (size_t)arow * D + kk * 32 + kbase;
    alo[kk] = *(const f32x4*)s;
    ahi[kk] = *(const f32x4*)(s + 4);
  }
  bf16x8 xfrag[4];
#pragma unroll
  for (int kk = 0; kk < 4; ++kk) {
    u32x4 w;
    w[0] = packbf2(alo[kk][0], alo[kk][1]);
    w[1] = packbf2(alo[kk][2], alo[kk][3]);
    w[2] = packbf2(ahi[kk][0], ahi[kk][1]);
    w[3] = packbf2(ahi[kk][2], ahi[kk][3]);
    xfrag[kk] = __builtin_bit_cast(bf16x8, w);
  }

  f32x4 acc[12];
#pragma unroll
  for (int c = 0; c < 12; ++c) acc[c] = (f32x4)(0.f);

#pragma unroll
  for (int kk = 0; kk < 4; ++kk) {
    bf16x8 wfrag[12];
#pragma unroll
    for (int c = 0; c < 12; ++c) {
      const int ct = (c >> 2) * 8 + chalf * 4 + (c & 3);
      wfrag[c] = *(const bf16x8*)(wseq + (size_t)((ct * 4 + kk) * 64 + lane) * 8);
    }
#pragma unroll
    for (int c = 0; c < 12; ++c)   // A = W, B = X (swapped)
      acc[c] = __builtin_amdgcn_mfma_f32_16x16x32_bf16(wfrag[c], xfrag[kk], acc[c], 0, 0, 0);
  }

  // D layout (swapped): lane holds out[row=m0+(l&15)][tile*16+(l>>4)*4+r]
  const int outrow = m0 + r16;
  const int cg = (lane >> 4) * 4;
  if (outrow < n) {
#pragma unroll
    for (int i = 0; i < 4; ++i) {
      const int colq = (chalf * 4 + i) * 16 + cg;
      u32x2 qw;
      qw[0] = packbf2(acc[i][0], acc[i][1]);
      qw[1] = packbf2(acc[i][2], acc[i][3]);
      *(u32x2*)&qb[(size_t)outrow * 128 + colq] = qw;          // 8B store
      u32x4 kvw;
#pragma unroll
      for (int r = 0; r < 4; ++r)
        kvw[r] = (unsigned)(u16)f2bf(acc[4 + i][r])            // k lo
               | ((unsigned)(u16)f2bf(acc[8 + i][r]) << 16);   // v hi
      *(u32x4*)&kv[(size_t)outrow * 256 + 2 * colq] = kvw;     // 16B store
    }
  }
}

// ---------------- Per-node attention ----------------
struct QPack {
#if HAS_DOT2
  unsigned qp[4];
#else
  float q0, q1, q2, q3;
#endif
};

template <int NU>
__device__ inline void attn_edges(const short* __restrict__ kv, int tj, int j0,
                                  int deg, int last, unsigned boff, int half,
                                  const QPack& qq, float& asum, f32x4& acc,
                                  bool masked) {
  int ts[NU];
  bool act[NU];
#pragma unroll
  for (int u = 0; u < NU; ++u) {
    const int idx = j0 + 2 * u + half;
    act[u] = !masked || (idx < deg);
    ts[u] = __shfl(tj, masked ? min(idx, last) : idx);
  }
  bf16x8 kvv[NU];
#pragma unroll
  for (int u = 0; u < NU; ++u)
    kvv[u] = *(const bf16x8*)(kv + (((unsigned)ts[u] << 8) + boff));
#pragma unroll
  for (int u = 0; u < NU; ++u) {
    const u32x4 w = __builtin_bit_cast(u32x4, kvv[u]);
#if HAS_DOT2
    float pd = fdot2bf(w[0], qq.qp[0], 0.f);
    pd = fdot2bf(w[1], qq.qp[1], pd);
    pd = fdot2bf(w[2], qq.qp[2], pd);
    pd = fdot2bf(w[3], qq.qp[3], pd);
    pd = quad_reduce_add(pd);
    float e = __expf(fminf(fmaxf(pd, -40.f), 40.f) * SCALE);
    if (masked) e = act[u] ? e : 0.f;
    asum += e;
    const unsigned epk = __float_as_uint(e) & 0xffff0000u;  // (0, bf16_trunc(e))
    acc[0] = fdot2bf(w[0], epk, acc[0]);
    acc[1] = fdot2bf(w[1], epk, acc[1]);
    acc[2] = fdot2bf(w[2], epk, acc[2]);
    acc[3] = fdot2bf(w[3], epk, acc[3]);
#else
    float pd = __uint_as_float(w[0] << 16) * qq.q0 + __uint_as_float(w[1] << 16) * qq.q1 +
               __uint_as_float(w[2] << 16) * qq.q2 + __uint_as_float(w[3] << 16) * qq.q3;
    pd = quad_reduce_add(pd);
    float e = __expf(fminf(fmaxf(pd, -10.f), 10.f));
    if (masked) e = act[u] ? e : 0.f;
    asum += e;
    acc[0] += e * __uint_as_float(w[0] & 0xffff0000u);
    acc[1] += e * __uint_as_float(w[1] & 0xffff0000u);
    acc[2] += e * __uint_as_float(w[2] & 0xffff0000u);
    acc[3] += e * __uint_as_float(w[3] & 0xffff0000u);
#endif
  }
}

__global__ __launch_bounds__(256) void attn_kernel(
    const short* __restrict__ qb, const short* __restrict__ kv,
    const int* __restrict__ cntx, const u16* __restrict__ etgtx,
    short* __restrict__ ab, int n) {
  const int wid = (blockIdx.x * 256 + threadIdx.x) >> 6;
  if (wid >= n) return;
  const int lane = threadIdx.x & 63;
  const int sl = lane & 31;
  const int half = lane >> 5;

  int cx = (lane < NXCD) ? cntx[(size_t)lane * n + wid] : 0;
  int deg = 0;
  int p[NXCD], c[NXCD];
#pragma unroll
  for (int x = 0; x < NXCD; ++x) {
    c[x] = min(__shfl(cx, x), CAP);
    p[x] = deg;
    deg += c[x];
  }

  if (deg == 0) {
    if (half == 0) {
      ushort4 z = {0, 0, 0, 0};
      *(ushort4*)&ab[(size_t)wid * 128 + sl * 4] = z;
    }
    return;
  }

  int tj = 0;
#pragma unroll
  for (int x = 0; x < NXCD; ++x) {
    int off = lane - p[x];
    if (off >= 0 && off < c[x]) tj = (int)etgtx[(((size_t)x * n + wid) << 4) + off];
  }

  const ushort4 q4 = *(const ushort4*)&qb[(size_t)wid * 128 + sl * 4];
  QPack qq;
#if HAS_DOT2
  qq.qp[0] = (unsigned)q4.x;
  qq.qp[1] = (unsigned)q4.y;
  qq.qp[2] = (unsigned)q4.z;
  qq.qp[3] = (unsigned)q4.w;
#else
  qq.q0 = bf2f(q4.x) * SCALE;  qq.q1 = bf2f(q4.y) * SCALE;
  qq.q2 = bf2f(q4.z) * SCALE;  qq.q3 = bf2f(q4.w) * SCALE;
#endif

  f32x4 acc = (f32x4)(0.f);
  float asum = 0.f;
  const unsigned boff = (unsigned)sl * 8;
  const int last = deg - 1;

  int j = 0;
  for (; j + 16 <= deg; j += 16)
    attn_edges<8>(kv, tj, j, deg, last, boff, half, qq, asum, acc, false);
  const int rem = deg - j;
  if (rem > 8)      attn_edges<8>(kv, tj, j, deg, last, boff, half, qq, asum, acc, true);
  else if (rem > 0) attn_edges<4>(kv, tj, j, deg, last, boff, half, qq, asum, acc, true);

  asum += __shfl_xor(asum, 32);
#pragma unroll
  for (int i = 0; i < 4; ++i) acc[i] += __shfl_xor(acc[i], 32);

  if (half == 0) {
    const float inv = 1.f / (asum + 1e-8f);
    ushort4 o;
    o.x = (u16)f2bf(acc[0] * inv);
    o.y = (u16)f2bf(acc[1] * inv);
    o.z = (u16)f2bf(acc[2] * inv);
    o.w = (u16)f2bf(acc[3] * inv);
    *(ushort4*)&ab[(size_t)wid * 128 + sl * 4] = o;
  }
}

// ------- Output projection via MFMA (swapped operands -> f32x4 stores) -----
__global__ __launch_bounds__(256) void out_mfma(
    const short* __restrict__ ab, const short* __restrict__ wseqO,
    float* __restrict__ out, int n) {
  const int lane = threadIdx.x & 63;
  const int m0 = blockIdx.x * 64 + (threadIdx.x >> 6) * 16;
  const int r16 = lane & 15;
  const int kbase = (lane >> 4) * 8;
  const int arow = min(m0 + r16, n - 1);

  bf16x8 xfrag[4];
#pragma unroll
  for (int kk = 0; kk < 4; ++kk)
    xfrag[kk] = *(const bf16x8*)(ab + (size_t)arow * D + kk * 32 + kbase);

  f32x4 acc[8];
#pragma unroll
  for (int ct = 0; ct < 8; ++ct) acc[ct] = (f32x4)(0.f);

#pragma unroll
  for (int kk = 0; kk < 4; ++kk) {
    bf16x8 wfrag[8];
#pragma unroll
    for (int ct = 0; ct < 8; ++ct)
      wfrag[ct] = *(const bf16x8*)(wseqO + (size_t)((ct * 4 + kk) * 64 + lane) * 8);
#pragma unroll
    for (int ct = 0; ct < 8; ++ct)   // A = W, B = X (swapped)
      acc[ct] = __builtin_amdgcn_mfma_f32_16x16x32_bf16(wfrag[ct], xfrag[kk], acc[ct], 0, 0, 0);
  }

  const int outrow = m0 + r16;
  const int cg = (lane >> 4) * 4;
  if (outrow < n) {
#pragma unroll
    for (int ct = 0; ct < 8; ++ct)
      *(f32x4*)&out[(size_t)outrow * D + ct * 16 + cg] = acc[ct];
  }
}

extern "C" void kernel_launch(void* const* d_in, const int* in_sizes, int n_in,
                              void* d_out, int out_size, void* d_ws, size_t ws_size,
                              hipStream_t stream) {
  const float* embeds = (const float*)d_in[0];
  const int* ei = (const int*)d_in[1];
  const float* Wqkv = (const float*)d_in[2];
  const float* Wout = (const float*)d_in[3];
  float* out = (float*)d_out;

  const int n = in_sizes[0] / D;   // 50000
  const int E = in_sizes[1] / 2;   // 800000
  const size_t ND = (size_t)n * D;

  short* qb = (short*)d_ws;                 // n*128 bf16
  short* kv = qb + ND;                      // n*256 bf16 interleaved (k lo, v hi)
  short* wseq = kv + 2 * ND;                // 8192*8 bf16 frag-sequential weights
  int* cntx = (int*)(wseq + 65536);         // NXCD*n
  u16* etgtx = (u16*)(cntx + (size_t)NXCD * n);  // NXCD*n*CAP u16
  short* ab = qb;                           // alias: wave reads own q before write

  const int* esrc = ei;
  const int* etgt = ei + E;

  // ~50/50 edge split between the two fused dispatches (8 edges/thread)
  const int nb1 = (E / 2) / 2048;           // edges [0, nb1*2048)
  const int e1 = nb1 * 2048;
  const int nb2 = (E - e1 + 2047) / 2048;   // edges [e1, E)
  const int nqkv = (n + 31) / 32;

  hipMemsetAsync(cntx, 0, (size_t)NXCD * n * sizeof(int), stream);
  wcvt_build<<<32 + nb1, 256, 0, stream>>>(Wqkv, Wout, wseq, esrc, etgt, cntx, etgtx, n, e1);
  qkv_build<<<nb2 + nqkv, 256, 0, stream>>>(embeds, wseq, qb, kv, esrc, etgt, cntx, etgtx, n, E, e1, nb2);
  attn_kernel<<<((size_t)n * 64 + 255) / 256, 256, 0, stream>>>(qb, kv, cntx, etgtx, ab, n);
  out_mfma<<<(n + 63) / 64, 256, 0, stream>>>(ab, wseq + 24 * 4 * 64 * 8, out, n);
}

// Round 14
// 136.273 us; speedup vs baseline: 1.0086x; 1.0086x over previous
//
#include <hip/hip_runtime.h>

#define D 128
#define SCALE 0.25f
#define NHB 128      // histogram/scatter blocks (counting-sort slices)
#define MAXDEG 64    // padded CSR slots per node; P(deg>64)~0 for Poisson(16)

typedef __attribute__((ext_vector_type(8))) short bf16x8;
typedef __attribute__((ext_vector_type(4))) float f32x4;
typedef __attribute__((ext_vector_type(4))) unsigned int u32x4;
typedef __attribute__((ext_vector_type(2))) unsigned int u32x2;
typedef unsigned short u16;

#if __has_builtin(__builtin_amdgcn_fdot2_f32_bf16)
#define HAS_DOT2 1
typedef __attribute__((ext_vector_type(2))) __bf16 bf16x2;
__device__ inline float fdot2bf(unsigned a, unsigned b, float c) {
  return __builtin_amdgcn_fdot2_f32_bf16(__builtin_bit_cast(bf16x2, a),
                                         __builtin_bit_cast(bf16x2, b), c, false);
}
#else
#define HAS_DOT2 0
#endif

__device__ inline short f2bf(float f) {          // RNE float->bf16
  unsigned u = __float_as_uint(f);
  u += 0x7fff + ((u >> 16) & 1);
  return (short)(u >> 16);
}
__device__ inline float bf2f(u16 h) { return __uint_as_float(((unsigned)h) << 16); }
__device__ inline unsigned packbf2(float lo, float hi) {   // round-half-up pack
  unsigned a = __float_as_uint(lo) + 0x8000u;
  unsigned b = __float_as_uint(hi) + 0x8000u;
  return (a >> 16) | (b & 0xffff0000u);
}
// quad-lane butterfly add via DPP (pure VALU): l^1 then l^2
__device__ inline float quad_reduce_add(float p) {
  float t1 = __uint_as_float((unsigned)__builtin_amdgcn_update_dpp(
      0, (int)__float_as_uint(p), 0xB1, 0xf, 0xf, true));
  p += t1;
  float t2 = __uint_as_float((unsigned)__builtin_amdgcn_update_dpp(
      0, (int)__float_as_uint(p), 0x4E, 0xf, 0xf, true));
  return p + t2;
}

// ------ D1: per-slice LDS histogram (blocks [0,NHB)) + weight swizzle ------
// LDS: S/2 u32 words, 2 u16 bins packed per word (node v -> word v>>1,
// halfword v&1). Workgroup-scope LDS atomics only — no device atomics.
__global__ __launch_bounds__(256) void hist_wcvt(
    const float* __restrict__ Wqkv, const float* __restrict__ Wout,
    short* __restrict__ wseq, const int* __restrict__ esrc,
    unsigned* __restrict__ histG32, int n, int S, int E, int epb) {
  if ((int)blockIdx.x < NHB) {
    extern __shared__ unsigned lds32[];
    const int nw = S >> 1;
    for (int i = threadIdx.x; i < nw; i += 256) lds32[i] = 0u;
    __syncthreads();
    const int e0 = (int)blockIdx.x * epb;
    const int e1 = min(e0 + epb, E);
    for (int base = e0 + (int)threadIdx.x * 4; base < e1; base += 1024) {
      if (base + 3 < e1) {
        const int4 s4 = *(const int4*)(esrc + base);   // e0,epb mult of 4 -> aligned
        atomicAdd(&lds32[s4.x >> 1], 1u << ((s4.x & 1) * 16));
        atomicAdd(&lds32[s4.y >> 1], 1u << ((s4.y & 1) * 16));
        atomicAdd(&lds32[s4.z >> 1], 1u << ((s4.z & 1) * 16));
        atomicAdd(&lds32[s4.w >> 1], 1u << ((s4.w & 1) * 16));
      } else {
        for (int i = base; i < e1; ++i) {
          int v = esrc[i];
          atomicAdd(&lds32[v >> 1], 1u << ((v & 1) * 16));
        }
      }
    }
    __syncthreads();
    unsigned* dst = histG32 + (size_t)blockIdx.x * nw;
    for (int i = threadIdx.x; i < nw; i += 256) dst[i] = lds32[i];
    return;
  }

  // ---- weight swizzle (blocks NHB..NHB+32): fragment-sequential layout ----
  const int idx = ((int)blockIdx.x - NHB) * 256 + threadIdx.x;   // 8192 exact
  const int ct = idx >> 8, kk = (idx >> 6) & 3, lane = idx & 63;
  const float* W = (ct < 24) ? Wqkv : Wout;
  const int row = ((ct < 24) ? ct : ct - 24) * 16 + (lane & 15);
  const int col = kk * 32 + ((lane >> 4) << 3);
  const float* s = W + (size_t)row * 128 + col;
  bf16x8 o;
#pragma unroll
  for (int j = 0; j < 8; ++j) o[j] = f2bf(s[j]);
  *(bf16x8*)(wseq + (size_t)idx * 8) = o;
}

// ------ D2: per-node scan across slices (in-place base) + QKV MFMA ------
// Scan blocks [0,nscan): thread v converts histG16[b][v] -> exclusive base,
// accumulates cnt[v]. QKV blocks after: SWAPPED MFMA operands (A=W, B=X) ->
// lane holds out[row][4 consecutive cols] => contiguous 8B/16B stores.
__global__ __launch_bounds__(256) void scan_qkv(
    const float* __restrict__ embeds, const short* __restrict__ wseq,
    short* __restrict__ qb, short* __restrict__ kv,
    u16* __restrict__ histG16, unsigned* __restrict__ cnt,
    int n, int S, int nscan) {
  if ((int)blockIdx.x < nscan) {
    const int v = (int)blockIdx.x * 256 + (int)threadIdx.x;
    if (v < n) {
      unsigned run = 0;
      u16* p = histG16 + v;
#pragma unroll 4
      for (int b = 0; b < NHB; ++b) {
        unsigned x = *p;
        *p = (u16)run;
        run += x;
        p += S;
      }
      cnt[v] = run;
    }
    return;
  }

  // ---- QKV ----
  const int lane = threadIdx.x & 63;
  const int wave = threadIdx.x >> 6;
  const int m0 = ((int)blockIdx.x - nscan) * 32 + (wave >> 1) * 16;
  const int chalf = wave & 1;
  const int r16 = lane & 15;
  const int kbase = (lane >> 4) * 8;
  const int arow = min(m0 + r16, n - 1);

  f32x4 alo[4], ahi[4];
#pragma unroll
  for (int kk = 0; kk < 4; ++kk) {
    const float* s = embeds + (size_t)arow * D + kk * 32 + kbase;
    alo[kk] = *(const f32x4*)s;
    ahi[kk] = *(const f32x4*)(s + 4);
  }
  bf16x8 xfrag[4];
#pragma unroll
  for (int kk = 0; kk < 4; ++kk) {
    u32x4 w;
    w[0] = packbf2(alo[kk][0], alo[kk][1]);
    w[1] = packbf2(alo[kk][2], alo[kk][3]);
    w[2] = packbf2(ahi[kk][0], ahi[kk][1]);
    w[3] = packbf2(ahi[kk][2], ahi[kk][3]);
    xfrag[kk] = __builtin_bit_cast(bf16x8, w);
  }

  f32x4 acc[12];
#pragma unroll
  for (int c = 0; c < 12; ++c) acc[c] = (f32x4)(0.f);

#pragma unroll
  for (int kk = 0; kk < 4; ++kk) {
    bf16x8 wfrag[12];
#pragma unroll
    for (int c = 0; c < 12; ++c) {
      const int ct = (c >> 2) * 8 + chalf * 4 + (c & 3);
      wfrag[c] = *(const bf16x8*)(wseq + (size_t)((ct * 4 + kk) * 64 + lane) * 8);
    }
#pragma unroll
    for (int c = 0; c < 12; ++c)   // A = W, B = X (swapped)
      acc[c] = __builtin_amdgcn_mfma_f32_16x16x32_bf16(wfrag[c], xfrag[kk], acc[c], 0, 0, 0);
  }

  const int outrow = m0 + r16;
  const int cg = (lane >> 4) * 4;
  if (outrow < n) {
#pragma unroll
    for (int i = 0; i < 4; ++i) {
      const int colq = (chalf * 4 + i) * 16 + cg;
      u32x2 qw;
      qw[0] = packbf2(acc[i][0], acc[i][1]);
      qw[1] = packbf2(acc[i][2], acc[i][3]);
      *(u32x2*)&qb[(size_t)outrow * 128 + colq] = qw;          // 8B store
      u32x4 kvw;
#pragma unroll
      for (int r = 0; r < 4; ++r)
        kvw[r] = (unsigned)(u16)f2bf(acc[4 + i][r])            // k lo
               | ((unsigned)(u16)f2bf(acc[8 + i][r]) << 16);   // v hi
      *(u32x4*)&kv[(size_t)outrow * 256 + 2 * colq] = kvw;     // 16B store
    }
  }
}

// ------ D3: scatter — replay slice, LDS rank, store into padded CSR ------
__global__ __launch_bounds__(256) void scatter_kernel(
    const int* __restrict__ esrc, const int* __restrict__ etgt,
    const u16* __restrict__ bbase, u16* __restrict__ etgt16,
    int S, int E, int epb) {
  extern __shared__ unsigned lds32[];
  const int nw = S >> 1;
  for (int i = threadIdx.x; i < nw; i += 256) lds32[i] = 0u;
  __syncthreads();
  const u16* bb = bbase + (size_t)blockIdx.x * S;
  const int e0 = (int)blockIdx.x * epb;
  const int e1 = min(e0 + epb, E);
  for (int base = e0 + (int)threadIdx.x * 4; base < e1; base += 1024) {
    const int m = min(4, e1 - base);
    int vs[4], ts[4];
    if (m == 4) {
      const int4 s4 = *(const int4*)(esrc + base);
      vs[0] = s4.x; vs[1] = s4.y; vs[2] = s4.z; vs[3] = s4.w;
    } else {
#pragma unroll
      for (int j = 0; j < 4; ++j) vs[j] = (j < m) ? esrc[base + j] : 0;
    }
#pragma unroll
    for (int j = 0; j < 4; ++j) ts[j] = (j < m) ? etgt[base + j] : 0;
    unsigned pos[4];
#pragma unroll
    for (int j = 0; j < 4; ++j) {
      if (j < m) {
        unsigned old = atomicAdd(&lds32[vs[j] >> 1], 1u << ((vs[j] & 1) * 16));
        pos[j] = (old >> ((vs[j] & 1) * 16)) & 0xffffu;
      }
    }
#pragma unroll
    for (int j = 0; j < 4; ++j) if (j < m) pos[j] += (unsigned)bb[vs[j]];
#pragma unroll
    for (int j = 0; j < 4; ++j)
      if (j < m && pos[j] < MAXDEG)
        etgt16[((size_t)vs[j] << 6) + pos[j]] = (u16)ts[j];
  }
}

// ---------------- Per-node attention (padded-CSR preamble) ----------------
struct QPack {
#if HAS_DOT2
  unsigned qp[4];
#else
  float q0, q1, q2, q3;
#endif
};

template <int NU>
__device__ inline void attn_edges(const short* __restrict__ kv, int tj, int j0,
                                  int deg, int last, unsigned boff, int half,
                                  const QPack& qq, float& asum, f32x4& acc,
                                  bool masked) {
  int ts[NU];
  bool act[NU];
#pragma unroll
  for (int u = 0; u < NU; ++u) {
    const int idx = j0 + 2 * u + half;
    act[u] = !masked || (idx < deg);
    ts[u] = __shfl(tj, masked ? min(idx, last) : idx);
  }
  bf16x8 kvv[NU];
#pragma unroll
  for (int u = 0; u < NU; ++u)
    kvv[u] = *(const bf16x8*)(kv + (((unsigned)ts[u] << 8) + boff));
#pragma unroll
  for (int u = 0; u < NU; ++u) {
    const u32x4 w = __builtin_bit_cast(u32x4, kvv[u]);
#if HAS_DOT2
    float pd = fdot2bf(w[0], qq.qp[0], 0.f);
    pd = fdot2bf(w[1], qq.qp[1], pd);
    pd = fdot2bf(w[2], qq.qp[2], pd);
    pd = fdot2bf(w[3], qq.qp[3], pd);
    pd = quad_reduce_add(pd);
    float e = __expf(fminf(fmaxf(pd, -40.f), 40.f) * SCALE);
    if (masked) e = act[u] ? e : 0.f;
    asum += e;
    const unsigned epk = __float_as_uint(e) & 0xffff0000u;  // (0, bf16_trunc(e))
    acc[0] = fdot2bf(w[0], epk, acc[0]);
    acc[1] = fdot2bf(w[1], epk, acc[1]);
    acc[2] = fdot2bf(w[2], epk, acc[2]);
    acc[3] = fdot2bf(w[3], epk, acc[3]);
#else
    float pd = __uint_as_float(w[0] << 16) * qq.q0 + __uint_as_float(w[1] << 16) * qq.q1 +
               __uint_as_float(w[2] << 16) * qq.q2 + __uint_as_float(w[3] << 16) * qq.q3;
    pd = quad_reduce_add(pd);
    float e = __expf(fminf(fmaxf(pd, -10.f), 10.f));
    if (masked) e = act[u] ? e : 0.f;
    asum += e;
    acc[0] += e * __uint_as_float(w[0] & 0xffff0000u);
    acc[1] += e * __uint_as_float(w[1] & 0xffff0000u);
    acc[2] += e * __uint_as_float(w[2] & 0xffff0000u);
    acc[3] += e * __uint_as_float(w[3] & 0xffff0000u);
#endif
  }
}

__global__ __launch_bounds__(256) void attn_kernel(
    const short* __restrict__ qb, const short* __restrict__ kv,
    const unsigned* __restrict__ cnt, const u16* __restrict__ etgt16,
    short* __restrict__ ab, int n) {
  const int wid = (blockIdx.x * 256 + threadIdx.x) >> 6;
  if (wid >= n) return;
  const int lane = threadIdx.x & 63;
  const int sl = lane & 31;
  const int half = lane >> 5;

  const int deg = min((int)cnt[wid], MAXDEG);
  if (deg == 0) {
    if (half == 0) {
      ushort4 z = {0, 0, 0, 0};
      *(ushort4*)&ab[(size_t)wid * 128 + sl * 4] = z;
    }
    return;
  }
  // register-resident target list: lane L holds entry L (coalesced 2B read)
  const int tj = (lane < deg) ? (int)etgt16[((size_t)wid << 6) + lane] : 0;

  const ushort4 q4 = *(const ushort4*)&qb[(size_t)wid * 128 + sl * 4];
  QPack qq;
#if HAS_DOT2
  qq.qp[0] = (unsigned)q4.x;
  qq.qp[1] = (unsigned)q4.y;
  qq.qp[2] = (unsigned)q4.z;
  qq.qp[3] = (unsigned)q4.w;
#else
  qq.q0 = bf2f(q4.x) * SCALE;  qq.q1 = bf2f(q4.y) * SCALE;
  qq.q2 = bf2f(q4.z) * SCALE;  qq.q3 = bf2f(q4.w) * SCALE;
#endif

  f32x4 acc = (f32x4)(0.f);
  float asum = 0.f;
  const unsigned boff = (unsigned)sl * 8;
  const int last = deg - 1;

  int j = 0;
  for (; j + 16 <= deg; j += 16)
    attn_edges<8>(kv, tj, j, deg, last, boff, half, qq, asum, acc, false);
  const int rem = deg - j;
  if (rem > 8)      attn_edges<8>(kv, tj, j, deg, last, boff, half, qq, asum, acc, true);
  else if (rem > 0) attn_edges<4>(kv, tj, j, deg, last, boff, half, qq, asum, acc, true);

  asum += __shfl_xor(asum, 32);
#pragma unroll
  for (int i = 0; i < 4; ++i) acc[i] += __shfl_xor(acc[i], 32);

  if (half == 0) {
    const float inv = 1.f / (asum + 1e-8f);
    ushort4 o;
    o.x = (u16)f2bf(acc[0] * inv);
    o.y = (u16)f2bf(acc[1] * inv);
    o.z = (u16)f2bf(acc[2] * inv);
    o.w = (u16)f2bf(acc[3] * inv);
    *(ushort4*)&ab[(size_t)wid * 128 + sl * 4] = o;
  }
}

// ------- Output projection via MFMA (swapped operands -> f32x4 stores) -----
__global__ __launch_bounds__(256) void out_mfma(
    const short* __restrict__ ab, const short* __restrict__ wseqO,
    float* __restrict__ out, int n) {
  const int lane = threadIdx.x & 63;
  const int m0 = blockIdx.x * 64 + (threadIdx.x >> 6) * 16;
  const int r16 = lane & 15;
  const int kbase = (lane >> 4) * 8;
  const int arow = min(m0 + r16, n - 1);

  bf16x8 xfrag[4];
#pragma unroll
  for (int kk = 0; kk < 4; ++kk)
    xfrag[kk] = *(const bf16x8*)(ab + (size_t)arow * D + kk * 32 + kbase);

  f32x4 acc[8];
#pragma unroll
  for (int ct = 0; ct < 8; ++ct) acc[ct] = (f32x4)(0.f);

#pragma unroll
  for (int kk = 0; kk < 4; ++kk) {
    bf16x8 wfrag[8];
#pragma unroll
    for (int ct = 0; ct < 8; ++ct)
      wfrag[ct] = *(const bf16x8*)(wseqO + (size_t)((ct * 4 + kk) * 64 + lane) * 8);
#pragma unroll
    for (int ct = 0; ct < 8; ++ct)   // A = W, B = X (swapped)
      acc[ct] = __builtin_amdgcn_mfma_f32_16x16x32_bf16(wfrag[ct], xfrag[kk], acc[ct], 0, 0, 0);
  }

  const int outrow = m0 + r16;
  const int cg = (lane >> 4) * 4;
  if (outrow < n) {
#pragma unroll
    for (int ct = 0; ct < 8; ++ct)
      *(f32x4*)&out[(size_t)outrow * D + ct * 16 + cg] = acc[ct];
  }
}

extern "C" void kernel_launch(void* const* d_in, const int* in_sizes, int n_in,
                              void* d_out, int out_size, void* d_ws, size_t ws_size,
                              hipStream_t stream) {
  const float* embeds = (const float*)d_in[0];
  const int* ei = (const int*)d_in[1];
  const float* Wqkv = (const float*)d_in[2];
  const float* Wout = (const float*)d_in[3];
  float* out = (float*)d_out;

  const int n = in_sizes[0] / D;   // 50000
  const int E = in_sizes[1] / 2;   // 800000
  const size_t ND = (size_t)n * D;

  const int S = (n + 63) & ~63;                       // padded node count
  const int epb = (((E + NHB - 1) / NHB) + 3) & ~3;   // edges/slice, mult of 4
  const int nscan = (n + 255) / 256;
  const int nqkv = (n + 31) / 32;
  const unsigned ldsbytes = (unsigned)S * 2;          // ~100KB (<=160KB/WG)

  short* qb = (short*)d_ws;                 // n*128 bf16 (12.8MB)
  short* kv = qb + ND;                      // n*256 bf16 interleaved (25.6MB)
  short* wseq = kv + 2 * ND;                // 8192*8 bf16 frag-seq weights
  unsigned* histG32 = (unsigned*)(wseq + 65536);      // NHB*S/2 u32 (12.8MB)
  unsigned* cnt = histG32 + (size_t)NHB * (S >> 1);   // S u32 (0.2MB)
  u16* etgt16 = (u16*)(cnt + S);            // n*64 u16 padded CSR (6.4MB)
  short* ab = qb;                           // alias: wave reads own q first

  const int* esrc = ei;
  const int* etgt = ei + E;

  hist_wcvt<<<NHB + 32, 256, ldsbytes, stream>>>(Wqkv, Wout, wseq, esrc,
                                                 histG32, n, S, E, epb);
  scan_qkv<<<nscan + nqkv, 256, 0, stream>>>(embeds, wseq, qb, kv,
                                             (u16*)histG32, cnt, n, S, nscan);
  scatter_kernel<<<NHB, 256, ldsbytes, stream>>>(esrc, etgt, (const u16*)histG32,
                                                 etgt16, S, E, epb);
  attn_kernel<<<((size_t)n * 64 + 255) / 256, 256, 0, stream>>>(qb, kv, cnt, etgt16, ab, n);
  out_mfma<<<(n + 63) / 64, 256, 0, stream>>>(ab, wseq + 24 * 4 * 64 * 8, out, n);
}

// Round 15
// 135.504 us; speedup vs baseline: 1.0143x; 1.0057x over previous
//
#include <hip/hip_runtime.h>

#define D 128
#define SCALE 0.25f
#define NXCD 8
#define CAP 16     // per-(node,xcd) bucket; per-shard count ~Poisson(2)

typedef __attribute__((ext_vector_type(8))) short bf16x8;
typedef __attribute__((ext_vector_type(4))) float f32x4;
typedef __attribute__((ext_vector_type(4))) unsigned int u32x4;
typedef __attribute__((ext_vector_type(2))) unsigned int u32x2;
typedef unsigned short u16;

#if __has_builtin(__builtin_amdgcn_fdot2_f32_bf16)
#define HAS_DOT2 1
typedef __attribute__((ext_vector_type(2))) __bf16 bf16x2;
__device__ inline float fdot2bf(unsigned a, unsigned b, float c) {
  return __builtin_amdgcn_fdot2_f32_bf16(__builtin_bit_cast(bf16x2, a),
                                         __builtin_bit_cast(bf16x2, b), c, false);
}
#else
#define HAS_DOT2 0
#endif

__device__ inline short f2bf(float f) {          // RNE float->bf16
  unsigned u = __float_as_uint(f);
  u += 0x7fff + ((u >> 16) & 1);
  return (short)(u >> 16);
}
__device__ inline float bf2f(u16 h) { return __uint_as_float(((unsigned)h) << 16); }
__device__ inline unsigned packbf2(float lo, float hi) {   // round-half-up pack
  unsigned a = __float_as_uint(lo) + 0x8000u;
  unsigned b = __float_as_uint(hi) + 0x8000u;
  return (a >> 16) | (b & 0xffff0000u);
}
// quad-lane butterfly add via DPP (pure VALU): l^1 then l^2
__device__ inline float quad_reduce_add(float p) {
  float t1 = __uint_as_float((unsigned)__builtin_amdgcn_update_dpp(
      0, (int)__float_as_uint(p), 0xB1, 0xf, 0xf, true));
  p += t1;
  float t2 = __uint_as_float((unsigned)__builtin_amdgcn_update_dpp(
      0, (int)__float_as_uint(p), 0x4E, 0xf, 0xf, true));
  return p + t2;
}

// ---- build phase: 8 consecutive edges/thread, int4 loads, 8 independent
// atomic chains, then scatter stores. esrc/etgt separate pointers. ----
__device__ inline void build_edges8(const int* __restrict__ esrc,
                                    const int* __restrict__ etgt,
                                    int* __restrict__ cntx, u16* __restrict__ etgtx,
                                    int n, int elim, int e0base) {
  int xcd;
  asm volatile("s_getreg_b32 %0, hwreg(HW_REG_XCC_ID)" : "=s"(xcd));
  xcd &= (NXCD - 1);
  const int base = e0base + (int)threadIdx.x * 8;
  int s[8], t[8];
  if (base + 7 < elim) {
    *(int4*)&s[0] = *(const int4*)(esrc + base);
    *(int4*)&s[4] = *(const int4*)(esrc + base + 4);
    *(int4*)&t[0] = *(const int4*)(etgt + base);
    *(int4*)&t[4] = *(const int4*)(etgt + base + 4);
    int pos[8];
#pragma unroll
    for (int u = 0; u < 8; ++u)
      pos[u] = atomicAdd(&cntx[(size_t)xcd * n + s[u]], 1);
#pragma unroll
    for (int u = 0; u < 8; ++u)
      if (pos[u] < CAP) etgtx[(((size_t)xcd * n + s[u]) << 4) + pos[u]] = (u16)t[u];
  } else {
    for (int u = 0; u < 8; ++u) {
      const int i = base + u;
      if (i < elim) {
        const int ss = esrc[i];
        const int tt = etgt[i];
        const int pos = atomicAdd(&cntx[(size_t)xcd * n + ss], 1);
        if (pos < CAP) etgtx[(((size_t)xcd * n + ss) << 4) + pos] = (u16)tt;
      }
    }
  }
}

// ---------------- weight conversion (fragment-sequential swizzle) ----------
// wseq[((ct*4+kk)*64+lane)*8+j] = W[ct*16+(lane&15)][kk*32+(lane>>4)*8+j]
__global__ __launch_bounds__(256) void wcvt_kernel(
    const float* __restrict__ Wqkv, const float* __restrict__ Wout,
    short* __restrict__ wseq) {
  const int idx = blockIdx.x * 256 + threadIdx.x;   // grid 32*256 = 8192 exact
  const int ct = idx >> 8, kk = (idx >> 6) & 3, lane = idx & 63;
  const float* W = (ct < 24) ? Wqkv : Wout;
  const int row = ((ct < 24) ? ct : ct - 24) * 16 + (lane & 15);
  const int col = kk * 32 + ((lane >> 4) << 3);
  const float* s = W + (size_t)row * 128 + col;
  bf16x8 o;
#pragma unroll
  for (int j = 0; j < 8; ++j) o[j] = f2bf(s[j]);
  *(bf16x8*)(wseq + (size_t)idx * 8) = o;
}

// ------ Fused: XCD-sharded build (blocks FIRST) + QKV MFMA (swapped) ------
// Build blocks [0, nbuild) lead the dispatch so their atomic latency hides
// under the qkv compute tranches (R10 structure). QKV: SWAPPED operands
// (A=W, B=X) -> lane holds out[row=l&15][4 consecutive cols] => contiguous
// 8B (q) / 16B (kv-interleaved) stores (R11's store win, now unconfounded).
__global__ __launch_bounds__(256) void qkv_build(
    const float* __restrict__ embeds, const short* __restrict__ wseq,
    short* __restrict__ qb, short* __restrict__ kv,
    const int* __restrict__ esrc, const int* __restrict__ etgt,
    int* __restrict__ cntx, u16* __restrict__ etgtx,
    int n, int E, int nbuild) {
  if ((int)blockIdx.x < nbuild) {
    build_edges8(esrc, etgt, cntx, etgtx, n, E, (int)blockIdx.x * 2048);
    return;
  }

  // ---- QKV ----
  const int lane = threadIdx.x & 63;
  const int wave = threadIdx.x >> 6;
  const int m0 = ((int)blockIdx.x - nbuild) * 32 + (wave >> 1) * 16;
  const int chalf = wave & 1;
  const int r16 = lane & 15;
  const int kbase = (lane >> 4) * 8;
  const int arow = min(m0 + r16, n - 1);

  f32x4 alo[4], ahi[4];
#pragma unroll
  for (int kk = 0; kk < 4; ++kk) {
    const float* s = embeds + (size_t)arow * D + kk * 32 + kbase;
    alo[kk] = *(const f32x4*)s;
    ahi[kk] = *(const f32x4*)(s + 4);
  }
  bf16x8 xfrag[4];
#pragma unroll
  for (int kk = 0; kk < 4; ++kk) {
    u32x4 w;
    w[0] = packbf2(alo[kk][0], alo[kk][1]);
    w[1] = packbf2(alo[kk][2], alo[kk][3]);
    w[2] = packbf2(ahi[kk][0], ahi[kk][1]);
    w[3] = packbf2(ahi[kk][2], ahi[kk][3]);
    xfrag[kk] = __builtin_bit_cast(bf16x8, w);
  }

  f32x4 acc[12];
#pragma unroll
  for (int c = 0; c < 12; ++c) acc[c] = (f32x4)(0.f);

#pragma unroll
  for (int kk = 0; kk < 4; ++kk) {
    bf16x8 wfrag[12];
#pragma unroll
    for (int c = 0; c < 12; ++c) {
      const int ct = (c >> 2) * 8 + chalf * 4 + (c & 3);
      wfrag[c] = *(const bf16x8*)(wseq + (size_t)((ct * 4 + kk) * 64 + lane) * 8);
    }
#pragma unroll
    for (int c = 0; c < 12; ++c)   // A = W, B = X (swapped)
      acc[c] = __builtin_amdgcn_mfma_f32_16x16x32_bf16(wfrag[c], xfrag[kk], acc[c], 0, 0, 0);
  }

  // D layout (swapped): lane holds out[row=m0+(l&15)][tile*16+(l>>4)*4+r]
  const int outrow = m0 + r16;
  const int cg = (lane >> 4) * 4;
  if (outrow < n) {
#pragma unroll
    for (int i = 0; i < 4; ++i) {
      const int colq = (chalf * 4 + i) * 16 + cg;
      u32x2 qw;
      qw[0] = packbf2(acc[i][0], acc[i][1]);
      qw[1] = packbf2(acc[i][2], acc[i][3]);
      *(u32x2*)&qb[(size_t)outrow * 128 + colq] = qw;          // 8B store
      u32x4 kvw;
#pragma unroll
      for (int r = 0; r < 4; ++r)
        kvw[r] = (unsigned)(u16)f2bf(acc[4 + i][r])            // k lo
               | ((unsigned)(u16)f2bf(acc[8 + i][r]) << 16);   // v hi
      *(u32x4*)&kv[(size_t)outrow * 256 + 2 * colq] = kvw;     // 16B store
    }
  }
}

// ---------------- Per-node attention ----------------
struct QPack {
#if HAS_DOT2
  unsigned qp[4];
#else
  float q0, q1, q2, q3;
#endif
};

template <int NU>
__device__ inline void attn_edges(const short* __restrict__ kv, int tj, int j0,
                                  int deg, int last, unsigned boff, int half,
                                  const QPack& qq, float& asum, f32x4& acc,
                                  bool masked) {
  int ts[NU];
  bool act[NU];
#pragma unroll
  for (int u = 0; u < NU; ++u) {
    const int idx = j0 + 2 * u + half;
    act[u] = !masked || (idx < deg);
    ts[u] = __shfl(tj, masked ? min(idx, last) : idx);
  }
  bf16x8 kvv[NU];
#pragma unroll
  for (int u = 0; u < NU; ++u)
    kvv[u] = *(const bf16x8*)(kv + (((unsigned)ts[u] << 8) + boff));
#pragma unroll
  for (int u = 0; u < NU; ++u) {
    const u32x4 w = __builtin_bit_cast(u32x4, kvv[u]);
#if HAS_DOT2
    float pd = fdot2bf(w[0], qq.qp[0], 0.f);
    pd = fdot2bf(w[1], qq.qp[1], pd);
    pd = fdot2bf(w[2], qq.qp[2], pd);
    pd = fdot2bf(w[3], qq.qp[3], pd);
    pd = quad_reduce_add(pd);
    float e = __expf(fminf(fmaxf(pd, -40.f), 40.f) * SCALE);
    if (masked) e = act[u] ? e : 0.f;
    asum += e;
    const unsigned epk = __float_as_uint(e) & 0xffff0000u;  // (0, bf16_trunc(e))
    acc[0] = fdot2bf(w[0], epk, acc[0]);
    acc[1] = fdot2bf(w[1], epk, acc[1]);
    acc[2] = fdot2bf(w[2], epk, acc[2]);
    acc[3] = fdot2bf(w[3], epk, acc[3]);
#else
    float pd = __uint_as_float(w[0] << 16) * qq.q0 + __uint_as_float(w[1] << 16) * qq.q1 +
               __uint_as_float(w[2] << 16) * qq.q2 + __uint_as_float(w[3] << 16) * qq.q3;
    pd = quad_reduce_add(pd);
    float e = __expf(fminf(fmaxf(pd, -10.f), 10.f));
    if (masked) e = act[u] ? e : 0.f;
    asum += e;
    acc[0] += e * __uint_as_float(w[0] & 0xffff0000u);
    acc[1] += e * __uint_as_float(w[1] & 0xffff0000u);
    acc[2] += e * __uint_as_float(w[2] & 0xffff0000u);
    acc[3] += e * __uint_as_float(w[3] & 0xffff0000u);
#endif
  }
}

// __launch_bounds__(256, 4): cap 4 waves/EU (VGPR <= 128) so the compiler can
// keep the full 8-gather batch in flight (R14 showed VGPR=36 -> serialized).
__global__ __launch_bounds__(256, 4) void attn_kernel(
    const short* __restrict__ qb, const short* __restrict__ kv,
    const int* __restrict__ cntx, const u16* __restrict__ etgtx,
    short* __restrict__ ab, int n) {
  const int wid = (blockIdx.x * 256 + threadIdx.x) >> 6;
  if (wid >= n) return;
  const int lane = threadIdx.x & 63;
  const int sl = lane & 31;
  const int half = lane >> 5;

  int cx = (lane < NXCD) ? cntx[(size_t)lane * n + wid] : 0;
  int deg = 0;
  int p[NXCD], c[NXCD];
#pragma unroll
  for (int x = 0; x < NXCD; ++x) {
    c[x] = min(__shfl(cx, x), CAP);
    p[x] = deg;
    deg += c[x];
  }

  if (deg == 0) {
    if (half == 0) {
      ushort4 z = {0, 0, 0, 0};
      *(ushort4*)&ab[(size_t)wid * 128 + sl * 4] = z;
    }
    return;
  }

  int tj = 0;
#pragma unroll
  for (int x = 0; x < NXCD; ++x) {
    int off = lane - p[x];
    if (off >= 0 && off < c[x]) tj = (int)etgtx[(((size_t)x * n + wid) << 4) + off];
  }

  const ushort4 q4 = *(const ushort4*)&qb[(size_t)wid * 128 + sl * 4];
  QPack qq;
#if HAS_DOT2
  qq.qp[0] = (unsigned)q4.x;
  qq.qp[1] = (unsigned)q4.y;
  qq.qp[2] = (unsigned)q4.z;
  qq.qp[3] = (unsigned)q4.w;
#else
  qq.q0 = bf2f(q4.x) * SCALE;  qq.q1 = bf2f(q4.y) * SCALE;
  qq.q2 = bf2f(q4.z) * SCALE;  qq.q3 = bf2f(q4.w) * SCALE;
#endif

  f32x4 acc = (f32x4)(0.f);
  float asum = 0.f;
  const unsigned boff = (unsigned)sl * 8;
  const int last = deg - 1;

  int j = 0;
  for (; j + 16 <= deg; j += 16)
    attn_edges<8>(kv, tj, j, deg, last, boff, half, qq, asum, acc, false);
  const int rem = deg - j;
  if (rem > 8)      attn_edges<8>(kv, tj, j, deg, last, boff, half, qq, asum, acc, true);
  else if (rem > 0) attn_edges<4>(kv, tj, j, deg, last, boff, half, qq, asum, acc, true);

  asum += __shfl_xor(asum, 32);
#pragma unroll
  for (int i = 0; i < 4; ++i) acc[i] += __shfl_xor(acc[i], 32);

  if (half == 0) {
    const float inv = 1.f / (asum + 1e-8f);
    ushort4 o;
    o.x = (u16)f2bf(acc[0] * inv);
    o.y = (u16)f2bf(acc[1] * inv);
    o.z = (u16)f2bf(acc[2] * inv);
    o.w = (u16)f2bf(acc[3] * inv);
    *(ushort4*)&ab[(size_t)wid * 128 + sl * 4] = o;
  }
}

// ------- Output projection via MFMA (swapped operands -> f32x4 stores) -----
__global__ __launch_bounds__(256) void out_mfma(
    const short* __restrict__ ab, const short* __restrict__ wseqO,
    float* __restrict__ out, int n) {
  const int lane = threadIdx.x & 63;
  const int m0 = blockIdx.x * 64 + (threadIdx.x >> 6) * 16;
  const int r16 = lane & 15;
  const int kbase = (lane >> 4) * 8;
  const int arow = min(m0 + r16, n - 1);

  bf16x8 xfrag[4];
#pragma unroll
  for (int kk = 0; kk < 4; ++kk)
    xfrag[kk] = *(const bf16x8*)(ab + (size_t)arow * D + kk * 32 + kbase);

  f32x4 acc[8];
#pragma unroll
  for (int ct = 0; ct < 8; ++ct) acc[ct] = (f32x4)(0.f);

#pragma unroll
  for (int kk = 0; kk < 4; ++kk) {
    bf16x8 wfrag[8];
#pragma unroll
    for (int ct = 0; ct < 8; ++ct)
      wfrag[ct] = *(const bf16x8*)(wseqO + (size_t)((ct * 4 + kk) * 64 + lane) * 8);
#pragma unroll
    for (int ct = 0; ct < 8; ++ct)   // A = W, B = X (swapped)
      acc[ct] = __builtin_amdgcn_mfma_f32_16x16x32_bf16(wfrag[ct], xfrag[kk], acc[ct], 0, 0, 0);
  }

  const int outrow = m0 + r16;
  const int cg = (lane >> 4) * 4;
  if (outrow < n) {
#pragma unroll
    for (int ct = 0; ct < 8; ++ct)
      *(f32x4*)&out[(size_t)outrow * D + ct * 16 + cg] = acc[ct];
  }
}

extern "C" void kernel_launch(void* const* d_in, const int* in_sizes, int n_in,
                              void* d_out, int out_size, void* d_ws, size_t ws_size,
                              hipStream_t stream) {
  const float* embeds = (const float*)d_in[0];
  const int* ei = (const int*)d_in[1];
  const float* Wqkv = (const float*)d_in[2];
  const float* Wout = (const float*)d_in[3];
  float* out = (float*)d_out;

  const int n = in_sizes[0] / D;   // 50000
  const int E = in_sizes[1] / 2;   // 800000
  const size_t ND = (size_t)n * D;

  short* qb = (short*)d_ws;                 // n*128 bf16
  short* kv = qb + ND;                      // n*256 bf16 interleaved (k lo, v hi)
  short* wseq = kv + 2 * ND;                // 8192*8 bf16 frag-sequential weights
  int* cntx = (int*)(wseq + 65536);         // NXCD*n
  u16* etgtx = (u16*)(cntx + (size_t)NXCD * n);  // NXCD*n*CAP u16
  short* ab = qb;                           // alias: wave reads own q before write

  const int* esrc = ei;
  const int* etgt = ei + E;

  const int nbuild = (E + 2047) / 2048;     // 8 edges/thread
  const int nqkv = (n + 31) / 32;

  hipMemsetAsync(cntx, 0, (size_t)NXCD * n * sizeof(int), stream);
  wcvt_kernel<<<32, 256, 0, stream>>>(Wqkv, Wout, wseq);
  qkv_build<<<nbuild + nqkv, 256, 0, stream>>>(embeds, wseq, qb, kv, esrc, etgt, cntx, etgtx, n, E, nbuild);
  attn_kernel<<<((size_t)n * 64 + 255) / 256, 256, 0, stream>>>(qb, kv, cntx, etgtx, ab, n);
  out_mfma<<<(n + 63) / 64, 256, 0, stream>>>(ab, wseq + 24 * 4 * 64 * 8, out, n);
}